// Round 11
// baseline (35.401 us; speedup 1.0000x reference)
//
#include <hip/hip_runtime.h>
#include <math.h>

#ifndef USE_NEW_LARTG
#define USE_NEW_LARTG 1   // LAPACK >= 3.10 slartg convention
#endif

#define BB 256
#define NN 4096

// ============ float32 LAPACK-replica (ssyevd path for 3x3, lower) ============
// All arithmetic float32, FMA contraction off, mirroring netlib op order.
// DO NOT change op order / precision here: eigenvector SIGNS depend on the
// exact discrete path (round 1 failed from f64 vs f32 sweep-count mismatch).
// ZERO-ALLOCA: all state in NAMED SCALARS (R7/R8 lesson: arrays -> scratch).

__device__ __forceinline__ float ssign_(float a, float b) {
  return (b >= 0.0f) ? fabsf(a) : -fabsf(a);
}

__device__ __forceinline__ float slapy2f_(float x, float y) {
#pragma clang fp contract(off)
  float xa = fabsf(x), ya = fabsf(y);
  float w = fmaxf(xa, ya), z = fminf(xa, ya);
  if (z == 0.0f) return w;
  float q = z / w;
  return w * __fsqrt_rn(1.0f + q * q);
}

__device__ __forceinline__ void slartgf_(float f, float g, float& cs, float& sn, float& r) {
#pragma clang fp contract(off)
#if USE_NEW_LARTG
  if (g == 0.0f) { cs = 1.0f; sn = 0.0f; r = f; }
  else if (f == 0.0f) { cs = 0.0f; sn = (g >= 0.0f) ? 1.0f : -1.0f; r = fabsf(g); }
  else {
    float d = __fsqrt_rn(f * f + g * g);
    cs = fabsf(f) / d;
    r = ssign_(d, f);
    sn = g / r;
  }
#else
  if (g == 0.0f) { cs = 1.0f; sn = 0.0f; r = f; }
  else if (f == 0.0f) { cs = 0.0f; sn = 1.0f; r = g; }
  else {
    float rr = __fsqrt_rn(f * f + g * g);
    cs = f / rr; sn = g / rr; r = rr;
    if (fabsf(f) > fabsf(g) && cs < 0.0f) { cs = -cs; sn = -sn; r = -r; }
  }
#endif
}

__device__ __forceinline__ void slaev2f_(float a, float b, float c, float& rt1, float& rt2,
                                         float& cs1, float& sn1) {
#pragma clang fp contract(off)
  float sm = a + c;
  float df = a - c;
  float adf = fabsf(df);
  float tb = b + b;
  float ab = fabsf(tb);
  float acmx, acmn;
  if (fabsf(a) > fabsf(c)) { acmx = a; acmn = c; } else { acmx = c; acmn = a; }
  float rt;
  if (adf > ab)      { float q = ab / adf; rt = adf * __fsqrt_rn(1.0f + q * q); }
  else if (adf < ab) { float q = adf / ab; rt = ab * __fsqrt_rn(1.0f + q * q); }
  else               { rt = ab * __fsqrt_rn(2.0f); }
  int sgn1;
  if (sm < 0.0f)      { rt1 = 0.5f * (sm - rt); sgn1 = -1; rt2 = (acmx / rt1) * acmn - (b / rt1) * b; }
  else if (sm > 0.0f) { rt1 = 0.5f * (sm + rt); sgn1 = 1;  rt2 = (acmx / rt1) * acmn - (b / rt1) * b; }
  else                { rt1 = 0.5f * rt; rt2 = -0.5f * rt; sgn1 = 1; }
  float cs;
  int sgn2;
  if (df >= 0.0f) { cs = df + rt; sgn2 = 1; } else { cs = df - rt; sgn2 = -1; }
  float acs = fabsf(cs);
  if (acs > ab) {
    float ct = -tb / cs;
    sn1 = 1.0f / __fsqrt_rn(1.0f + ct * ct);
    cs1 = ct * sn1;
  } else {
    if (ab == 0.0f) { cs1 = 1.0f; sn1 = 0.0f; }
    else { float tn = -cs / tb; cs1 = 1.0f / __fsqrt_rn(1.0f + tn * tn); sn1 = tn * cs1; }
  }
  if (sgn1 == sgn2) { float tn = cs1; cs1 = -sn1; sn1 = tn; }
}

// ---- named-scalar access macros (no arrays -> no scratch possible) ----
#define DGET(i)   ((i) == 1 ? d1 : ((i) == 2 ? d2 : d3))
#define DSET(i,v) do { float _t = (v); int _i = (i); \
  d1 = (_i == 1) ? _t : d1; d2 = (_i == 2) ? _t : d2; d3 = (_i == 3) ? _t : d3; } while (0)
#define EGET(i)   ((i) == 1 ? e1 : e2)
#define ESET(i,v) do { float _t = (v); int _i = (i); \
  e1 = (_i == 1) ? _t : e1; e2 = (_i == 2) ? _t : e2; } while (0)
#define WCGET(i)  ((i) == 1 ? wc1 : wc2)
#define WSGET(i)  ((i) == 1 ? ws1 : ws2)
#define WCSET(i,v) do { float _t = (v); int _i = (i); \
  wc1 = (_i == 1) ? _t : wc1; wc2 = (_i == 2) ? _t : wc2; } while (0)
#define WSSET(i,v) do { float _t = (v); int _i = (i); \
  ws1 = (_i == 1) ? _t : ws1; ws2 = (_i == 2) ? _t : ws2; } while (0)
#define ZGETR(rr,j) ((j) == 1 ? z##rr##1 : ((j) == 2 ? z##rr##2 : z##rr##3))
#define ZSETR(rr,j,v) do { float _zv = (v); int _zj = (j); \
  z##rr##1 = (_zj == 1) ? _zv : z##rr##1; \
  z##rr##2 = (_zj == 2) ? _zv : z##rr##2; \
  z##rr##3 = (_zj == 3) ? _zv : z##rr##3; } while (0)
#define ROTR(rr, hi, lo, cc, ss) do { \
  float _zh = ZGETR(rr, (hi)); float _zl = ZGETR(rr, (lo)); \
  float _nh = (cc) * _zh - (ss) * _zl; \
  float _nl = (ss) * _zh + (cc) * _zl; \
  ZSETR(rr, (hi), _nh); ZSETR(rr, (lo), _nl); } while (0)
#define ROTCOLS(hi, lo, cc, ss) do { \
  ROTR(1, hi, lo, cc, ss); ROTR(2, hi, lo, cc, ss); ROTR(3, hi, lo, cc, ss); } while (0)
#define ZSWAPR(rr, i_, k_) do { \
  float _ta = ZGETR(rr, (i_)); float _tb = ZGETR(rr, (k_)); \
  ZSETR(rr, (i_), _tb); ZSETR(rr, (k_), _ta); } while (0)

// Full ssyevd path for 3x3 symmetric (lower): ssytd2 + ssteqr('I') + Householder.
__device__ __forceinline__ void eigh3_reg(const float C[3][3], float V[3][3]) {
#pragma clang fp contract(off)
  const float eps = 5.9604645e-08f;
  const float eps2 = eps * eps;
  const float safmin = 1.17549435e-38f;
  const int nmaxit = 90;

  float a11 = C[0][0], a21 = C[1][0], a31 = C[2][0];
  float a22 = C[1][1], a32 = C[2][1], a33 = C[2][2];
  float d1, d2, d3, e1, e2, tau1, v3;
  float z11, z12, z13, z21, z22, z23, z31, z32, z33;
  float wc1 = 0.0f, wc2 = 0.0f, ws1 = 0.0f, ws2 = 0.0f;
  int jtot = 0, l1 = 1;
  int m, l, lend, lsv, lendsv, i, j, k, ii;
  float p, g, r, c, s, f, b, rt1, rt2, tst, anorm, cj, sj;

  float xnorm = fabsf(a31);
  if (xnorm == 0.0f) {
    tau1 = 0.0f; v3 = 0.0f;
    d1 = a11; d2 = a22; d3 = a33; e1 = a21; e2 = a32;
  } else {
    float beta = -ssign_(slapy2f_(a21, xnorm), a21);
    tau1 = (beta - a21) / beta;
    v3 = a31 / (a21 - beta);
    e1 = beta;
    float x1 = tau1 * a22 + tau1 * (a32 * v3);
    float x2 = tau1 * a32 + (tau1 * v3) * a33;
    float al = -0.5f * tau1 * (x1 + x2 * v3);
    float w1 = x1 + al;
    float w2 = x2 + al * v3;
    d1 = a11;
    d2 = (a22 - w1) - w1;
    e2 = (a32 - v3 * w1) - w2;
    d3 = (a33 - v3 * w2) - w2 * v3;
  }
  z11 = 1.0f; z12 = 0.0f; z13 = 0.0f;
  z21 = 0.0f; z22 = 1.0f; z23 = 0.0f;
  z31 = 0.0f; z32 = 0.0f; z33 = 1.0f;

L10:
  if (l1 > 3) goto L160;
  if (l1 > 1) ESET(l1 - 1, 0.0f);
  if (l1 <= 2) {
    for (int mm = l1; mm <= 2; ++mm) {
      tst = fabsf(EGET(mm));
      if (tst == 0.0f) { m = mm; goto L30; }
      if (tst <= (__fsqrt_rn(fabsf(DGET(mm))) * __fsqrt_rn(fabsf(DGET(mm + 1)))) * eps) {
        ESET(mm, 0.0f); m = mm; goto L30;
      }
    }
  }
  m = 3;
L30:
  l = l1; lsv = l; lend = m; lendsv = lend; l1 = m + 1;
  if (lend == l) goto L10;
  anorm = 0.0f;
  for (i = l; i <= lend; ++i) anorm = fmaxf(anorm, fabsf(DGET(i)));
  for (i = l; i <= lend - 1; ++i) anorm = fmaxf(anorm, fabsf(EGET(i)));
  if (anorm == 0.0f) goto L10;
  if (fabsf(DGET(lend)) < fabsf(DGET(l))) { lend = lsv; l = lendsv; }

  if (lend > l) {
    // ---------------- QL iteration ----------------
L40:
    if (l != lend) {
      for (int mm = l; mm <= lend - 1; ++mm) {
        tst = EGET(mm) * EGET(mm);
        if (tst <= (eps2 * fabsf(DGET(mm))) * fabsf(DGET(mm + 1)) + safmin) { m = mm; goto L60; }
      }
    }
    m = lend;
L60:
    if (m < lend) ESET(m, 0.0f);
    p = DGET(l);
    if (m == l) goto L80;
    if (m == l + 1) {
      slaev2f_(DGET(l), EGET(l), DGET(l + 1), rt1, rt2, c, s);
      WCSET(l, c); WSSET(l, s);
      ROTCOLS(l + 1, l, c, s);
      DSET(l, rt1); DSET(l + 1, rt2); ESET(l, 0.0f);
      l = l + 2;
      if (l <= lend) goto L40;
      goto L140;
    }
    if (jtot == nmaxit) goto L140;
    jtot = jtot + 1;
    g = (DGET(l + 1) - p) / (2.0f * EGET(l));
    r = slapy2f_(g, 1.0f);
    g = DGET(m) - p + EGET(l) / (g + ssign_(r, g));
    s = 1.0f; c = 1.0f; p = 0.0f;
    for (i = m - 1; i >= l; --i) {
      f = s * EGET(i); b = c * EGET(i);
      slartgf_(g, f, c, s, r);
      if (i != m - 1) ESET(i + 1, r);
      g = DGET(i + 1) - p;
      r = (DGET(i) - g) * s + 2.0f * c * b;
      p = s * r;
      DSET(i + 1, g + p);
      g = c * r - b;
      WCSET(i, c); WSSET(i, -s);
    }
    for (j = (m - l + 1) - 1; j >= 1; --j) {
      cj = WCGET(l + j - 1); sj = WSGET(l + j - 1);
      ROTCOLS(l + j, l + j - 1, cj, sj);
    }
    DSET(l, DGET(l) - p);
    ESET(l, g);
    goto L40;
L80:
    DSET(l, p);
    l = l + 1;
    if (l <= lend) goto L40;
    goto L140;
  } else {
    // ---------------- QR iteration ----------------
L90:
    if (l != lend) {
      for (int mm = l; mm >= lend + 1; --mm) {
        tst = EGET(mm - 1) * EGET(mm - 1);
        if (tst <= (eps2 * fabsf(DGET(mm))) * fabsf(DGET(mm - 1)) + safmin) { m = mm; goto L110; }
      }
    }
    m = lend;
L110:
    if (m > lend) ESET(m - 1, 0.0f);
    p = DGET(l);
    if (m == l) goto L130;
    if (m == l - 1) {
      slaev2f_(DGET(l - 1), EGET(l - 1), DGET(l), rt1, rt2, c, s);
      WCSET(m, c); WSSET(m, s);
      ROTCOLS(l, l - 1, c, s);
      DSET(l - 1, rt1); DSET(l, rt2); ESET(l - 1, 0.0f);
      l = l - 2;
      if (l >= lend) goto L90;
      goto L140;
    }
    if (jtot == nmaxit) goto L140;
    jtot = jtot + 1;
    g = (DGET(l - 1) - p) / (2.0f * EGET(l - 1));
    r = slapy2f_(g, 1.0f);
    g = DGET(m) - p + EGET(l - 1) / (g + ssign_(r, g));
    s = 1.0f; c = 1.0f; p = 0.0f;
    for (i = m; i <= l - 1; ++i) {
      f = s * EGET(i); b = c * EGET(i);
      slartgf_(g, f, c, s, r);
      if (i != m) ESET(i - 1, r);
      g = DGET(i) - p;
      r = (DGET(i + 1) - g) * s + 2.0f * c * b;
      p = s * r;
      DSET(i, g + p);
      g = c * r - b;
      WCSET(i, c); WSSET(i, s);
    }
    for (j = 1; j <= (l - m + 1) - 1; ++j) {
      cj = WCGET(m + j - 1); sj = WSGET(m + j - 1);
      ROTCOLS(m + j, m + j - 1, cj, sj);
    }
    DSET(l, DGET(l) - p);
    ESET(l - 1, g);
    goto L90;
L130:
    DSET(l, p);
    l = l - 1;
    if (l >= lend) goto L90;
    goto L140;
  }
L140:
  if (jtot < nmaxit) goto L10;
  goto L190;
L160:
  for (ii = 2; ii <= 3; ++ii) {
    i = ii - 1; k = i; p = DGET(i);
    for (j = ii; j <= 3; ++j) {
      float dj = DGET(j);
      if (dj < p) { k = j; p = dj; }
    }
    if (k != i) {
      DSET(k, DGET(i)); DSET(i, p);
      ZSWAPR(1, i, k); ZSWAPR(2, i, k); ZSWAPR(3, i, k);
    }
  }
L190:
  if (tau1 != 0.0f) {
    float wj, tmp;
    wj = z21 + z31 * v3; tmp = -(tau1 * wj); z21 = z21 + tmp; z31 = z31 + v3 * tmp;
    wj = z22 + z32 * v3; tmp = -(tau1 * wj); z22 = z22 + tmp; z32 = z32 + v3 * tmp;
    wj = z23 + z33 * v3; tmp = -(tau1 * wj); z23 = z23 + tmp; z33 = z33 + v3 * tmp;
  }
  V[0][0] = z11; V[0][1] = z12; V[0][2] = z13;
  V[1][0] = z21; V[1][1] = z22; V[1][2] = z23;
  V[2][0] = z31; V[2][1] = z32; V[2][2] = z33;
}

// ====================== Single fused kernel, one block per batch ======================
// 256 blocks x 1024 threads (1 block/CU, 16 waves). Each thread owns 4 points
// of its batch: load ONCE, accumulate moments, hold in registers, apply after
// the eigh. Zero read amplification, zero reloads, 1 launch.
__global__ __launch_bounds__(1024, 4) void k_fused2(
    const float* __restrict__ X, const float* __restrict__ mask,
    float* __restrict__ out_fops, float* __restrict__ out_center,
    float* __restrict__ h) {
  int b = blockIdx.x;
  int t = threadIdx.x;   // 0..1023

  const float4* Xv = reinterpret_cast<const float4*>(X);
  const float4* Mv = reinterpret_cast<const float4*>(mask);

  // ---- Phase A: load own 4 points, accumulate 11 f64 moments ----
  int fi = b * 3072 + 3 * t;
  float4 v0 = Xv[fi], v1 = Xv[fi + 1], v2 = Xv[fi + 2];
  float4 mm = Mv[b * 1024 + t];
  float px[4] = {v0.x, v0.w, v1.z, v2.y};
  float py[4] = {v0.y, v1.x, v1.w, v2.z};
  float pz[4] = {v0.z, v1.y, v2.x, v2.w};
  float pm[4] = {mm.x, mm.y, mm.z, mm.w};

  double acc[11];
#pragma unroll
  for (int q = 0; q < 11; ++q) acc[q] = 0.0;
#pragma unroll
  for (int q = 0; q < 4; ++q) {
    double x = px[q], y = py[q], zz = pz[q], m = pm[q];
    acc[0] += m;       acc[1] += m * m;
    acc[2] += m * x;   acc[3] += m * y;   acc[4] += m * zz;
    acc[5] += x * x;   acc[6] += x * y;   acc[7] += x * zz;
    acc[8] += y * y;   acc[9] += y * zz;  acc[10] += zz * zz;
  }
#pragma unroll
  for (int off = 32; off > 0; off >>= 1)
#pragma unroll
    for (int q = 0; q < 11; ++q) acc[q] += __shfl_down(acc[q], off, 64);

  __shared__ double sh[16][11];
  int wid = t >> 6, lane = t & 63;
  if (lane == 0)
    for (int q = 0; q < 11; ++q) sh[wid][q] = acc[q];
  __syncthreads();

  // ---- Phase B: thread 0 combines 16 wave partials (fixed order) + eigh ----
  __shared__ float svc[12];
  if (t == 0) {
    double r[11];
#pragma unroll
    for (int q = 0; q < 11; ++q) {
      double s = 0.0;
      for (int w = 0; w < 16; ++w) s += sh[w][q];
      r[q] = s;
    }
    double W = r[0], W2 = r[1];
    double ssum[3] = {r[2], r[3], r[4]};
    double M[3][3] = {{r[5], r[6], r[7]}, {r[6], r[8], r[9]}, {r[7], r[9], r[10]}};
    double cc[3] = {ssum[0] / W, ssum[1] / W, ssum[2] / W};
    float Cf[3][3];
#pragma unroll
    for (int i = 0; i < 3; ++i)
#pragma unroll
      for (int j = 0; j < 3; ++j)
        Cf[i][j] = (float)(M[i][j] - (ssum[i] * cc[j] + cc[i] * ssum[j]) + W2 * cc[i] * cc[j]);
    float Vf[3][3];
    eigh3_reg(Cf, Vf);
    float cf[3] = {(float)cc[0], (float)cc[1], (float)cc[2]};
#pragma unroll
    for (int i = 0; i < 3; ++i)
#pragma unroll
      for (int j = 0; j < 3; ++j) svc[i * 3 + j] = Vf[i][j];
    svc[9] = cf[0]; svc[10] = cf[1]; svc[11] = cf[2];
    out_center[b * 3 + 0] = cf[0];
    out_center[b * 3 + 1] = cf[1];
    out_center[b * 3 + 2] = cf[2];
#pragma unroll
    for (int o = 0; o < 8; ++o) {
      float sgn[3] = {(o & 4) ? 1.f : -1.f, (o & 2) ? 1.f : -1.f, (o & 1) ? 1.f : -1.f};
#pragma unroll
      for (int i = 0; i < 3; ++i)
#pragma unroll
        for (int j = 0; j < 3; ++j)
          out_fops[b * 72 + o * 9 + i * 3 + j] = sgn[j] * Vf[i][j];
    }
  }
  __syncthreads();

  float V0 = svc[0], V1 = svc[1], V2 = svc[2];
  float V3 = svc[3], V4 = svc[4], V5 = svc[5];
  float V6 = svc[6], V7 = svc[7], V8 = svc[8];
  float c0 = svc[9], c1 = svc[10], c2 = svc[11];

  // ---- Phase C: apply from held registers ----
  float ya[4], yb[4], yc[4];
#pragma unroll
  for (int q = 0; q < 4; ++q) {
    float xcx = px[q] - c0 * pm[q];
    float xcy = py[q] - c1 * pm[q];
    float xcz = pz[q] - c2 * pm[q];
    ya[q] = V0 * xcx + V3 * xcy + V6 * xcz;
    yb[q] = V1 * xcx + V4 * xcy + V7 * xcz;
    yc[q] = V2 * xcx + V5 * xcy + V8 * xcz;
  }

  // Stage full batch's y in LDS in exact output float layout (48 KB).
  __shared__ float ylds[12288];
  float4* yv = reinterpret_cast<float4*>(ylds);
  yv[3 * t]     = make_float4(ya[0], yb[0], yc[0], ya[1]);
  yv[3 * t + 1] = make_float4(yb[1], yc[1], ya[2], yb[2]);
  yv[3 * t + 2] = make_float4(yc[2], ya[3], yb[3], yc[3]);
  __syncthreads();

  uint4 r0 = reinterpret_cast<const uint4*>(ylds)[t];
  uint4 r1 = reinterpret_cast<const uint4*>(ylds)[t + 1024];
  uint4 r2 = reinterpret_cast<const uint4*>(ylds)[t + 2048];

  // Leading comp of slot s = s%3; 1024%3==1, 2048%3==2 -> t%3,(t+1)%3,(t+2)%3.
  int c0i = t % 3;
  bool ee0 = (c0i == 0), ee1 = (c0i == 1);

  uint4* hv = reinterpret_cast<uint4*>(h);
  int hb = 3072 * (b * 8);
#pragma unroll
  for (int o = 0; o < 8; ++o) {
    unsigned s0 = (o & 4) ? 0u : 0x80000000u;
    unsigned s1 = (o & 2) ? 0u : 0x80000000u;
    unsigned s2 = (o & 1) ? 0u : 0x80000000u;
    unsigned ma = ee0 ? s0 : (ee1 ? s1 : s2);
    unsigned mb = ee0 ? s1 : (ee1 ? s2 : s0);
    unsigned mc = ee0 ? s2 : (ee1 ? s0 : s1);
    int base = hb + 3072 * o;
    hv[base + t]        = make_uint4(r0.x ^ ma, r0.y ^ mb, r0.z ^ mc, r0.w ^ ma);
    hv[base + t + 1024] = make_uint4(r1.x ^ mb, r1.y ^ mc, r1.z ^ ma, r1.w ^ mb);
    hv[base + t + 2048] = make_uint4(r2.x ^ mc, r2.y ^ ma, r2.z ^ mb, r2.w ^ mc);
  }
}

// ====================== launch ======================
extern "C" void kernel_launch(void* const* d_in, const int* in_sizes, int n_in,
                              void* d_out, int out_size, void* d_ws, size_t ws_size,
                              hipStream_t stream) {
  const float* X = (const float*)d_in[0];
  const float* mask = (const float*)d_in[1];
  float* out = (float*)d_out;
  float* h = out;                                        // [B*8, N, 3]
  float* fops = out + (size_t)BB * 8 * NN * 3;           // [B, 8, 3, 3]
  float* center = fops + (size_t)BB * 8 * 9;             // [B, 3]

  hipLaunchKernelGGL(k_fused2, dim3(BB), dim3(1024), 0, stream,
                     X, mask, fops, center, h);
}

// Round 12
// 31.936 us; speedup vs baseline: 1.1085x; 1.1085x over previous
//
#include <hip/hip_runtime.h>
#include <math.h>

#ifndef USE_NEW_LARTG
#define USE_NEW_LARTG 1   // LAPACK >= 3.10 slartg convention
#endif

#define BB 256
#define NN 4096

// ============ float32 LAPACK-replica (ssyevd path for 3x3, lower) ============
// All arithmetic float32, FMA contraction off, mirroring netlib op order.
// DO NOT change op order / precision here: eigenvector SIGNS depend on the
// exact discrete path (round 1 failed from f64 vs f32 sweep-count mismatch).
// ZERO-ALLOCA: all state in NAMED SCALARS (R7/R8 lesson: arrays -> scratch).

__device__ __forceinline__ float ssign_(float a, float b) {
  return (b >= 0.0f) ? fabsf(a) : -fabsf(a);
}

__device__ __forceinline__ float slapy2f_(float x, float y) {
#pragma clang fp contract(off)
  float xa = fabsf(x), ya = fabsf(y);
  float w = fmaxf(xa, ya), z = fminf(xa, ya);
  if (z == 0.0f) return w;
  float q = z / w;
  return w * __fsqrt_rn(1.0f + q * q);
}

__device__ __forceinline__ void slartgf_(float f, float g, float& cs, float& sn, float& r) {
#pragma clang fp contract(off)
#if USE_NEW_LARTG
  if (g == 0.0f) { cs = 1.0f; sn = 0.0f; r = f; }
  else if (f == 0.0f) { cs = 0.0f; sn = (g >= 0.0f) ? 1.0f : -1.0f; r = fabsf(g); }
  else {
    float d = __fsqrt_rn(f * f + g * g);
    cs = fabsf(f) / d;
    r = ssign_(d, f);
    sn = g / r;
  }
#else
  if (g == 0.0f) { cs = 1.0f; sn = 0.0f; r = f; }
  else if (f == 0.0f) { cs = 0.0f; sn = 1.0f; r = g; }
  else {
    float rr = __fsqrt_rn(f * f + g * g);
    cs = f / rr; sn = g / rr; r = rr;
    if (fabsf(f) > fabsf(g) && cs < 0.0f) { cs = -cs; sn = -sn; r = -r; }
  }
#endif
}

__device__ __forceinline__ void slaev2f_(float a, float b, float c, float& rt1, float& rt2,
                                         float& cs1, float& sn1) {
#pragma clang fp contract(off)
  float sm = a + c;
  float df = a - c;
  float adf = fabsf(df);
  float tb = b + b;
  float ab = fabsf(tb);
  float acmx, acmn;
  if (fabsf(a) > fabsf(c)) { acmx = a; acmn = c; } else { acmx = c; acmn = a; }
  float rt;
  if (adf > ab)      { float q = ab / adf; rt = adf * __fsqrt_rn(1.0f + q * q); }
  else if (adf < ab) { float q = adf / ab; rt = ab * __fsqrt_rn(1.0f + q * q); }
  else               { rt = ab * __fsqrt_rn(2.0f); }
  int sgn1;
  if (sm < 0.0f)      { rt1 = 0.5f * (sm - rt); sgn1 = -1; rt2 = (acmx / rt1) * acmn - (b / rt1) * b; }
  else if (sm > 0.0f) { rt1 = 0.5f * (sm + rt); sgn1 = 1;  rt2 = (acmx / rt1) * acmn - (b / rt1) * b; }
  else                { rt1 = 0.5f * rt; rt2 = -0.5f * rt; sgn1 = 1; }
  float cs;
  int sgn2;
  if (df >= 0.0f) { cs = df + rt; sgn2 = 1; } else { cs = df - rt; sgn2 = -1; }
  float acs = fabsf(cs);
  if (acs > ab) {
    float ct = -tb / cs;
    sn1 = 1.0f / __fsqrt_rn(1.0f + ct * ct);
    cs1 = ct * sn1;
  } else {
    if (ab == 0.0f) { cs1 = 1.0f; sn1 = 0.0f; }
    else { float tn = -cs / tb; cs1 = 1.0f / __fsqrt_rn(1.0f + tn * tn); sn1 = tn * cs1; }
  }
  if (sgn1 == sgn2) { float tn = cs1; cs1 = -sn1; sn1 = tn; }
}

// ---- named-scalar access macros (no arrays -> no scratch possible) ----
#define DGET(i)   ((i) == 1 ? d1 : ((i) == 2 ? d2 : d3))
#define DSET(i,v) do { float _t = (v); int _i = (i); \
  d1 = (_i == 1) ? _t : d1; d2 = (_i == 2) ? _t : d2; d3 = (_i == 3) ? _t : d3; } while (0)
#define EGET(i)   ((i) == 1 ? e1 : e2)
#define ESET(i,v) do { float _t = (v); int _i = (i); \
  e1 = (_i == 1) ? _t : e1; e2 = (_i == 2) ? _t : e2; } while (0)
#define WCGET(i)  ((i) == 1 ? wc1 : wc2)
#define WSGET(i)  ((i) == 1 ? ws1 : ws2)
#define WCSET(i,v) do { float _t = (v); int _i = (i); \
  wc1 = (_i == 1) ? _t : wc1; wc2 = (_i == 2) ? _t : wc2; } while (0)
#define WSSET(i,v) do { float _t = (v); int _i = (i); \
  ws1 = (_i == 1) ? _t : ws1; ws2 = (_i == 2) ? _t : ws2; } while (0)
#define ZGETR(rr,j) ((j) == 1 ? z##rr##1 : ((j) == 2 ? z##rr##2 : z##rr##3))
#define ZSETR(rr,j,v) do { float _zv = (v); int _zj = (j); \
  z##rr##1 = (_zj == 1) ? _zv : z##rr##1; \
  z##rr##2 = (_zj == 2) ? _zv : z##rr##2; \
  z##rr##3 = (_zj == 3) ? _zv : z##rr##3; } while (0)
#define ROTR(rr, hi, lo, cc, ss) do { \
  float _zh = ZGETR(rr, (hi)); float _zl = ZGETR(rr, (lo)); \
  float _nh = (cc) * _zh - (ss) * _zl; \
  float _nl = (ss) * _zh + (cc) * _zl; \
  ZSETR(rr, (hi), _nh); ZSETR(rr, (lo), _nl); } while (0)
#define ROTCOLS(hi, lo, cc, ss) do { \
  ROTR(1, hi, lo, cc, ss); ROTR(2, hi, lo, cc, ss); ROTR(3, hi, lo, cc, ss); } while (0)
#define ZSWAPR(rr, i_, k_) do { \
  float _ta = ZGETR(rr, (i_)); float _tb = ZGETR(rr, (k_)); \
  ZSETR(rr, (i_), _tb); ZSETR(rr, (k_), _ta); } while (0)

// Full ssyevd path for 3x3 symmetric (lower): ssytd2 + ssteqr('I') + Householder.
__device__ __forceinline__ void eigh3_reg(const float C[3][3], float V[3][3]) {
#pragma clang fp contract(off)
  const float eps = 5.9604645e-08f;
  const float eps2 = eps * eps;
  const float safmin = 1.17549435e-38f;
  const int nmaxit = 90;

  float a11 = C[0][0], a21 = C[1][0], a31 = C[2][0];
  float a22 = C[1][1], a32 = C[2][1], a33 = C[2][2];
  float d1, d2, d3, e1, e2, tau1, v3;
  float z11, z12, z13, z21, z22, z23, z31, z32, z33;
  float wc1 = 0.0f, wc2 = 0.0f, ws1 = 0.0f, ws2 = 0.0f;
  int jtot = 0, l1 = 1;
  int m, l, lend, lsv, lendsv, i, j, k, ii;
  float p, g, r, c, s, f, b, rt1, rt2, tst, anorm, cj, sj;

  float xnorm = fabsf(a31);
  if (xnorm == 0.0f) {
    tau1 = 0.0f; v3 = 0.0f;
    d1 = a11; d2 = a22; d3 = a33; e1 = a21; e2 = a32;
  } else {
    float beta = -ssign_(slapy2f_(a21, xnorm), a21);
    tau1 = (beta - a21) / beta;
    v3 = a31 / (a21 - beta);
    e1 = beta;
    float x1 = tau1 * a22 + tau1 * (a32 * v3);
    float x2 = tau1 * a32 + (tau1 * v3) * a33;
    float al = -0.5f * tau1 * (x1 + x2 * v3);
    float w1 = x1 + al;
    float w2 = x2 + al * v3;
    d1 = a11;
    d2 = (a22 - w1) - w1;
    e2 = (a32 - v3 * w1) - w2;
    d3 = (a33 - v3 * w2) - w2 * v3;
  }
  z11 = 1.0f; z12 = 0.0f; z13 = 0.0f;
  z21 = 0.0f; z22 = 1.0f; z23 = 0.0f;
  z31 = 0.0f; z32 = 0.0f; z33 = 1.0f;

L10:
  if (l1 > 3) goto L160;
  if (l1 > 1) ESET(l1 - 1, 0.0f);
  if (l1 <= 2) {
    for (int mm = l1; mm <= 2; ++mm) {
      tst = fabsf(EGET(mm));
      if (tst == 0.0f) { m = mm; goto L30; }
      if (tst <= (__fsqrt_rn(fabsf(DGET(mm))) * __fsqrt_rn(fabsf(DGET(mm + 1)))) * eps) {
        ESET(mm, 0.0f); m = mm; goto L30;
      }
    }
  }
  m = 3;
L30:
  l = l1; lsv = l; lend = m; lendsv = lend; l1 = m + 1;
  if (lend == l) goto L10;
  anorm = 0.0f;
  for (i = l; i <= lend; ++i) anorm = fmaxf(anorm, fabsf(DGET(i)));
  for (i = l; i <= lend - 1; ++i) anorm = fmaxf(anorm, fabsf(EGET(i)));
  if (anorm == 0.0f) goto L10;
  if (fabsf(DGET(lend)) < fabsf(DGET(l))) { lend = lsv; l = lendsv; }

  if (lend > l) {
    // ---------------- QL iteration ----------------
L40:
    if (l != lend) {
      for (int mm = l; mm <= lend - 1; ++mm) {
        tst = EGET(mm) * EGET(mm);
        if (tst <= (eps2 * fabsf(DGET(mm))) * fabsf(DGET(mm + 1)) + safmin) { m = mm; goto L60; }
      }
    }
    m = lend;
L60:
    if (m < lend) ESET(m, 0.0f);
    p = DGET(l);
    if (m == l) goto L80;
    if (m == l + 1) {
      slaev2f_(DGET(l), EGET(l), DGET(l + 1), rt1, rt2, c, s);
      WCSET(l, c); WSSET(l, s);
      ROTCOLS(l + 1, l, c, s);
      DSET(l, rt1); DSET(l + 1, rt2); ESET(l, 0.0f);
      l = l + 2;
      if (l <= lend) goto L40;
      goto L140;
    }
    if (jtot == nmaxit) goto L140;
    jtot = jtot + 1;
    g = (DGET(l + 1) - p) / (2.0f * EGET(l));
    r = slapy2f_(g, 1.0f);
    g = DGET(m) - p + EGET(l) / (g + ssign_(r, g));
    s = 1.0f; c = 1.0f; p = 0.0f;
    for (i = m - 1; i >= l; --i) {
      f = s * EGET(i); b = c * EGET(i);
      slartgf_(g, f, c, s, r);
      if (i != m - 1) ESET(i + 1, r);
      g = DGET(i + 1) - p;
      r = (DGET(i) - g) * s + 2.0f * c * b;
      p = s * r;
      DSET(i + 1, g + p);
      g = c * r - b;
      WCSET(i, c); WSSET(i, -s);
    }
    for (j = (m - l + 1) - 1; j >= 1; --j) {
      cj = WCGET(l + j - 1); sj = WSGET(l + j - 1);
      ROTCOLS(l + j, l + j - 1, cj, sj);
    }
    DSET(l, DGET(l) - p);
    ESET(l, g);
    goto L40;
L80:
    DSET(l, p);
    l = l + 1;
    if (l <= lend) goto L40;
    goto L140;
  } else {
    // ---------------- QR iteration ----------------
L90:
    if (l != lend) {
      for (int mm = l; mm >= lend + 1; --mm) {
        tst = EGET(mm - 1) * EGET(mm - 1);
        if (tst <= (eps2 * fabsf(DGET(mm))) * fabsf(DGET(mm - 1)) + safmin) { m = mm; goto L110; }
      }
    }
    m = lend;
L110:
    if (m > lend) ESET(m - 1, 0.0f);
    p = DGET(l);
    if (m == l) goto L130;
    if (m == l - 1) {
      slaev2f_(DGET(l - 1), EGET(l - 1), DGET(l), rt1, rt2, c, s);
      WCSET(m, c); WSSET(m, s);
      ROTCOLS(l, l - 1, c, s);
      DSET(l - 1, rt1); DSET(l, rt2); ESET(l - 1, 0.0f);
      l = l - 2;
      if (l >= lend) goto L90;
      goto L140;
    }
    if (jtot == nmaxit) goto L140;
    jtot = jtot + 1;
    g = (DGET(l - 1) - p) / (2.0f * EGET(l - 1));
    r = slapy2f_(g, 1.0f);
    g = DGET(m) - p + EGET(l - 1) / (g + ssign_(r, g));
    s = 1.0f; c = 1.0f; p = 0.0f;
    for (i = m; i <= l - 1; ++i) {
      f = s * EGET(i); b = c * EGET(i);
      slartgf_(g, f, c, s, r);
      if (i != m) ESET(i - 1, r);
      g = DGET(i) - p;
      r = (DGET(i + 1) - g) * s + 2.0f * c * b;
      p = s * r;
      DSET(i, g + p);
      g = c * r - b;
      WCSET(i, c); WSSET(i, s);
    }
    for (j = 1; j <= (l - m + 1) - 1; ++j) {
      cj = WCGET(m + j - 1); sj = WSGET(m + j - 1);
      ROTCOLS(m + j, m + j - 1, cj, sj);
    }
    DSET(l, DGET(l) - p);
    ESET(l - 1, g);
    goto L90;
L130:
    DSET(l, p);
    l = l - 1;
    if (l >= lend) goto L90;
    goto L140;
  }
L140:
  if (jtot < nmaxit) goto L10;
  goto L190;
L160:
  for (ii = 2; ii <= 3; ++ii) {
    i = ii - 1; k = i; p = DGET(i);
    for (j = ii; j <= 3; ++j) {
      float dj = DGET(j);
      if (dj < p) { k = j; p = dj; }
    }
    if (k != i) {
      DSET(k, DGET(i)); DSET(i, p);
      ZSWAPR(1, i, k); ZSWAPR(2, i, k); ZSWAPR(3, i, k);
    }
  }
L190:
  if (tau1 != 0.0f) {
    float wj, tmp;
    wj = z21 + z31 * v3; tmp = -(tau1 * wj); z21 = z21 + tmp; z31 = z31 + v3 * tmp;
    wj = z22 + z32 * v3; tmp = -(tau1 * wj); z22 = z22 + tmp; z32 = z32 + v3 * tmp;
    wj = z23 + z33 * v3; tmp = -(tau1 * wj); z23 = z23 + tmp; z33 = z33 + v3 * tmp;
  }
  V[0][0] = z11; V[0][1] = z12; V[0][2] = z13;
  V[1][0] = z21; V[1][1] = z22; V[1][2] = z23;
  V[2][0] = z31; V[2][1] = z32; V[2][2] = z33;
}

// ====================== Single fused kernel (R10 + sibling-same-XCD swizzle) ==========
// 1024 blocks x 256 threads (4/CU). Mapping: b = blk & 255, chunk = blk >> 8.
// Since 256 % 8 == 0, the 4 sibling blocks {b, b+256, b+512, b+768} all land on
// XCD b%8 -> the 4x-amplified phase-A reads of batch b are served by ONE shared
// per-XCD L2 (64KB batch << 4MB L2) instead of 4 separate L2s missing to L3.
__global__ __launch_bounds__(256, 4) void k_fused1(
    const float* __restrict__ X, const float* __restrict__ mask,
    float* __restrict__ out_fops, float* __restrict__ out_center,
    float* __restrict__ h) {
  int blk = blockIdx.x;
  int b = blk & 255;       // sibling blocks 256 apart -> same XCD (256 % 8 == 0)
  int chunk = blk >> 8;
  int t = threadIdx.x;

  const float4* Xv = reinterpret_cast<const float4*>(X);
  const float4* Mv = reinterpret_cast<const float4*>(mask);

  // ---- Phase A: full-batch moments, fixed order (kk ascending) ----
  double acc[11];
#pragma unroll
  for (int q = 0; q < 11; ++q) acc[q] = 0.0;
  for (int kk = 0; kk < 4; ++kk) {
    int fi = b * 3072 + kk * 768 + 3 * t;
    float4 v0 = Xv[fi], v1 = Xv[fi + 1], v2 = Xv[fi + 2];
    float4 mm = Mv[b * 1024 + kk * 256 + t];
    float px[4] = {v0.x, v0.w, v1.z, v2.y};
    float py[4] = {v0.y, v1.x, v1.w, v2.z};
    float pz[4] = {v0.z, v1.y, v2.x, v2.w};
    float pm[4] = {mm.x, mm.y, mm.z, mm.w};
#pragma unroll
    for (int q = 0; q < 4; ++q) {
      double x = px[q], y = py[q], zz = pz[q], m = pm[q];
      acc[0] += m;       acc[1] += m * m;
      acc[2] += m * x;   acc[3] += m * y;   acc[4] += m * zz;
      acc[5] += x * x;   acc[6] += x * y;   acc[7] += x * zz;
      acc[8] += y * y;   acc[9] += y * zz;  acc[10] += zz * zz;
    }
  }
#pragma unroll
  for (int off = 32; off > 0; off >>= 1)
#pragma unroll
    for (int q = 0; q < 11; ++q) acc[q] += __shfl_down(acc[q], off, 64);

  __shared__ double sh[4][11];
  int wid = t >> 6, lane = t & 63;
  if (lane == 0)
    for (int q = 0; q < 11; ++q) sh[wid][q] = acc[q];
  __syncthreads();

  // ---- Issue own-chunk reloads now (land during eigh; same-XCD L2-hot) ----
  int fi = b * 3072 + chunk * 768 + 3 * t;
  float4 v0 = Xv[fi], v1 = Xv[fi + 1], v2 = Xv[fi + 2];
  float4 mm = Mv[b * 1024 + chunk * 256 + t];

  // ---- Phase B: thread 0 combines (fixed order) + eigh ----
  __shared__ float svc[12];
  if (t == 0) {
    double r[11];
#pragma unroll
    for (int q = 0; q < 11; ++q)
      r[q] = sh[0][q] + sh[1][q] + sh[2][q] + sh[3][q];
    double W = r[0], W2 = r[1];
    double ssum[3] = {r[2], r[3], r[4]};
    double M[3][3] = {{r[5], r[6], r[7]}, {r[6], r[8], r[9]}, {r[7], r[9], r[10]}};
    double cc[3] = {ssum[0] / W, ssum[1] / W, ssum[2] / W};
    float Cf[3][3];
#pragma unroll
    for (int i = 0; i < 3; ++i)
#pragma unroll
      for (int j = 0; j < 3; ++j)
        Cf[i][j] = (float)(M[i][j] - (ssum[i] * cc[j] + cc[i] * ssum[j]) + W2 * cc[i] * cc[j]);
    float Vf[3][3];
    eigh3_reg(Cf, Vf);
    float cf[3] = {(float)cc[0], (float)cc[1], (float)cc[2]};
#pragma unroll
    for (int i = 0; i < 3; ++i)
#pragma unroll
      for (int j = 0; j < 3; ++j) svc[i * 3 + j] = Vf[i][j];
    svc[9] = cf[0]; svc[10] = cf[1]; svc[11] = cf[2];
    if (chunk == 0) {
      out_center[b * 3 + 0] = cf[0];
      out_center[b * 3 + 1] = cf[1];
      out_center[b * 3 + 2] = cf[2];
#pragma unroll
      for (int o = 0; o < 8; ++o) {
        float sgn[3] = {(o & 4) ? 1.f : -1.f, (o & 2) ? 1.f : -1.f, (o & 1) ? 1.f : -1.f};
#pragma unroll
        for (int i = 0; i < 3; ++i)
#pragma unroll
          for (int j = 0; j < 3; ++j)
            out_fops[b * 72 + o * 9 + i * 3 + j] = sgn[j] * Vf[i][j];
      }
    }
  }
  __syncthreads();

  float V0 = svc[0], V1 = svc[1], V2 = svc[2];
  float V3 = svc[3], V4 = svc[4], V5 = svc[5];
  float V6 = svc[6], V7 = svc[7], V8 = svc[8];
  float c0 = svc[9], c1 = svc[10], c2 = svc[11];

  // ---- Phase C: apply to own chunk ----
  float px[4] = {v0.x, v0.w, v1.z, v2.y};
  float py[4] = {v0.y, v1.x, v1.w, v2.z};
  float pz[4] = {v0.z, v1.y, v2.x, v2.w};
  float pm[4] = {mm.x, mm.y, mm.z, mm.w};

  float ya[4], yb[4], yc[4];
#pragma unroll
  for (int q = 0; q < 4; ++q) {
    float xcx = px[q] - c0 * pm[q];
    float xcy = py[q] - c1 * pm[q];
    float xcz = pz[q] - c2 * pm[q];
    ya[q] = V0 * xcx + V3 * xcy + V6 * xcz;
    yb[q] = V1 * xcx + V4 * xcy + V7 * xcz;
    yc[q] = V2 * xcx + V5 * xcy + V8 * xcz;
  }

  __shared__ float ylds[3072];  // 12 KB, exact output float layout
  float4* yv = reinterpret_cast<float4*>(ylds);
  yv[3 * t]     = make_float4(ya[0], yb[0], yc[0], ya[1]);
  yv[3 * t + 1] = make_float4(yb[1], yc[1], ya[2], yb[2]);
  yv[3 * t + 2] = make_float4(yc[2], ya[3], yb[3], yc[3]);
  __syncthreads();

  uint4 r0 = reinterpret_cast<const uint4*>(ylds)[t];
  uint4 r1 = reinterpret_cast<const uint4*>(ylds)[t + 256];
  uint4 r2 = reinterpret_cast<const uint4*>(ylds)[t + 512];

  int c0i = t % 3;
  bool ee0 = (c0i == 0), ee1 = (c0i == 1);

  uint4* hv = reinterpret_cast<uint4*>(h);
  int hb = 3072 * (b * 8) + 768 * chunk;
#pragma unroll
  for (int o = 0; o < 8; ++o) {
    unsigned s0 = (o & 4) ? 0u : 0x80000000u;
    unsigned s1 = (o & 2) ? 0u : 0x80000000u;
    unsigned s2 = (o & 1) ? 0u : 0x80000000u;
    unsigned ma = ee0 ? s0 : (ee1 ? s1 : s2);
    unsigned mb = ee0 ? s1 : (ee1 ? s2 : s0);
    unsigned mc = ee0 ? s2 : (ee1 ? s0 : s1);
    int base = hb + 3072 * o;
    hv[base + t]       = make_uint4(r0.x ^ ma, r0.y ^ mb, r0.z ^ mc, r0.w ^ ma);
    hv[base + t + 256] = make_uint4(r1.x ^ mb, r1.y ^ mc, r1.z ^ ma, r1.w ^ mb);
    hv[base + t + 512] = make_uint4(r2.x ^ mc, r2.y ^ ma, r2.z ^ mb, r2.w ^ mc);
  }
}

// ====================== launch ======================
extern "C" void kernel_launch(void* const* d_in, const int* in_sizes, int n_in,
                              void* d_out, int out_size, void* d_ws, size_t ws_size,
                              hipStream_t stream) {
  const float* X = (const float*)d_in[0];
  const float* mask = (const float*)d_in[1];
  float* out = (float*)d_out;
  float* h = out;                                        // [B*8, N, 3]
  float* fops = out + (size_t)BB * 8 * NN * 3;           // [B, 8, 3, 3]
  float* center = fops + (size_t)BB * 8 * 9;             // [B, 3]

  hipLaunchKernelGGL(k_fused1, dim3(BB * 4), dim3(256), 0, stream,
                     X, mask, fops, center, h);
}